// Round 2
// baseline (161.601 us; speedup 1.0000x reference)
//
#include <hip/hip_runtime.h>
#include <math.h>

constexpr int Bsz   = 1024;
constexpr int S     = 512;
constexpr int SV    = 511;   // attention rows (all but last)
constexpr int D     = 32;
constexpr int F     = 4;
constexpr int H     = 64;
constexpr int BDIM  = 256;
constexpr int VOCAB = 100001;

__device__ __forceinline__ float fast_tanh(float x) {
  // tanh(x) = 1 - 2/(e^{2x}+1); exp overflow -> inf -> rcp -> 0 -> 1 (correct limit)
  const float ex = __expf(2.f * x);
  return 1.f - 2.f * __builtin_amdgcn_rcpf(ex + 1.f);
}

// ---- precompute fused gather table T[VOCAB][64] = [ emb_row | emb_row @ Wv ] ----
__global__ __launch_bounds__(BDIM) void build_table(
    const float* __restrict__ emb, const float* __restrict__ Wv,
    float* __restrict__ T, int vocab)
{
  __shared__ float sWv[D * D];
  for (int i = threadIdx.x; i < D * D; i += BDIM) sWv[i] = Wv[i];
  __syncthreads();
  const int lr  = threadIdx.x >> 5;       // 8 rows per block
  const int k   = threadIdx.x & 31;
  const int row = blockIdx.x * 8 + lr;
  if (row < vocab) {
    const float4* e4 = reinterpret_cast<const float4*>(emb + (size_t)row * D);
    float acc = 0.f;
    #pragma unroll
    for (int c = 0; c < 8; c++) {
      const float4 v = e4[c];
      acc += v.x * sWv[(4 * c + 0) * D + k] + v.y * sWv[(4 * c + 1) * D + k]
           + v.z * sWv[(4 * c + 2) * D + k] + v.w * sWv[(4 * c + 3) * D + k];
    }
    T[(size_t)row * 64 + k]      = emb[(size_t)row * D + k];
    T[(size_t)row * 64 + 32 + k] = acc;
  }
}

// ================= table-path main kernel =================
__global__ __launch_bounds__(BDIM) void attn_fused_tab(
    const float* __restrict__ values, const int* __restrict__ names,
    const float* __restrict__ T,          // [VOCAB,64] fused table
    const float* __restrict__ W_num, const float* __restrict__ b_num,
    const float* __restrict__ Wq,    const float* __restrict__ bq,
    const float* __restrict__ Wv,    const float* __restrict__ bv,
    const float* __restrict__ attn_scale,
    const float* __restrict__ Wp,    const float* __restrict__ bp,
    const float* __restrict__ ln_g,  const float* __restrict__ ln_b,
    const float* __restrict__ Ws,
    float* __restrict__ out_score, float* __restrict__ out_emb,
    float* __restrict__ out_attn,  float* __restrict__ out_h)
{
  __shared__ float sWnum[F * D];
  __shared__ float sbnum[D];
  __shared__ float sWq[D * D];
  __shared__ float sWv[D * D];
  __shared__ float sbv[D];
  __shared__ float sscale[D];
  __shared__ float sW2[F * D];      // W_num @ Wv
  __shared__ float sbias2[D];       // b_num @ Wv + bv
  __shared__ float sq[D];
  __shared__ float smixq[D];
  __shared__ float sred[4][72];     // per-wave {acc[32], esum[32], lloc, vsum[4]}
  __shared__ float sredS[4];
  __shared__ float sML[2];
  __shared__ float sctx[D];
  __shared__ float sWp[D * H];

  const int b    = blockIdx.x;
  const int tid  = threadIdx.x;
  const int lane = tid & 63;
  const int wv   = tid >> 6;

  // ---- stage weights ----
  for (int i = tid; i < F * D; i += BDIM) sWnum[i] = W_num[i];
  if (tid < D) { sbnum[tid] = b_num[tid]; sbv[tid] = bv[tid]; sscale[tid] = attn_scale[tid]; }
  for (int i = tid; i < D * D; i += BDIM) { sWq[i] = Wq[i]; sWv[i] = Wv[i]; }
  for (int i = tid; i < D * H; i += BDIM) sWp[i] = Wp[i];
  __syncthreads();

  // ---- derived small mats: W2 = W_num@Wv, bias2 = b_num@Wv + bv ----
  if (tid < F * D) {
    const int f = tid >> 5, k = tid & 31;
    float a = 0.f;
    #pragma unroll
    for (int m = 0; m < D; m++) a += sWnum[f * D + m] * sWv[m * D + k];
    sW2[f * D + k] = a;
  }
  if (tid >= F * D && tid < F * D + D) {
    const int k = tid - F * D;
    float a = sbv[k];
    #pragma unroll
    for (int m = 0; m < D; m++) a += sbnum[m] * sWv[m * D + k];
    sbias2[k] = a;
  }
  __syncthreads();

  // ---- query-row mix, q = mix_q @ Wq + bq ----
  if (tid < D) {
    const int    name = names[b * S + (S - 1)];
    const float* vr   = values + (size_t)(b * S + (S - 1)) * F;
    smixq[tid] = T[(size_t)name * 64 + tid] + sbnum[tid]
               + vr[0] * sWnum[tid] + vr[1] * sWnum[D + tid]
               + vr[2] * sWnum[2 * D + tid] + vr[3] * sWnum[3 * D + tid];
  }
  __syncthreads();
  if (tid < D) {
    float a = bq[tid];
    #pragma unroll
    for (int k = 0; k < D; k++) a += smixq[k] * sWq[k * D + tid];
    sq[tid] = a;
  }
  __syncthreads();

  // ---- per-thread row loop with online softmax ----
  float esum[D], acc[D];
  #pragma unroll
  for (int k = 0; k < D; k++) { esum[k] = 0.f; acc[k] = 0.f; }
  float vsum[F] = {0.f, 0.f, 0.f, 0.f};
  float mloc = -INFINITY, lloc = 0.f;
  float sc0 = 0.f, sc1 = 0.f;
  const bool has2 = (tid < SV - BDIM);  // tid < 255

  auto row = [&](int j, float& sout) {
    const int    name = names[b * S + j];
    const float4 v4   = *reinterpret_cast<const float4*>(values + (size_t)(b * S + j) * F);
    const float4* t4  = reinterpret_cast<const float4*>(T + (size_t)name * 64);
    float val[D];
    #pragma unroll
    for (int c = 0; c < 8; c++) {
      const float4 ev = t4[c];       // emb row -> esum only
      esum[4 * c] += ev.x; esum[4 * c + 1] += ev.y; esum[4 * c + 2] += ev.z; esum[4 * c + 3] += ev.w;
      const float4 wvv = t4[8 + c];  // emb@Wv row
      val[4 * c] = wvv.x; val[4 * c + 1] = wvv.y; val[4 * c + 2] = wvv.z; val[4 * c + 3] = wvv.w;
    }
    vsum[0] += v4.x; vsum[1] += v4.y; vsum[2] += v4.z; vsum[3] += v4.w;
    float s = 0.f;
    #pragma unroll
    for (int k = 0; k < D; k++) {
      val[k] += sbias2[k] + v4.x * sW2[k] + v4.y * sW2[D + k]
              + v4.z * sW2[2 * D + k] + v4.w * sW2[3 * D + k];
      s += sscale[k] * fast_tanh(sq[k] + val[k]);
    }
    sout = s;
    float w;
    if (s > mloc) {
      const float sf = __expf(mloc - s);   // exp(-inf)=0 handles first row
      lloc *= sf;
      #pragma unroll
      for (int k = 0; k < D; k++) acc[k] *= sf;
      mloc = s; w = 1.f;
    } else {
      w = __expf(s - mloc);
    }
    lloc += w;
    #pragma unroll
    for (int k = 0; k < D; k++) acc[k] += w * val[k];
  };

  row(tid, sc0);
  if (has2) row(tid + BDIM, sc1);

  // ---- block max of scores ----
  float mw = mloc;
  #pragma unroll
  for (int off = 32; off; off >>= 1) mw = fmaxf(mw, __shfl_xor(mw, off));
  if (lane == 0) sredS[wv] = mw;
  __syncthreads();
  if (tid == 0) sML[0] = fmaxf(fmaxf(sredS[0], sredS[1]), fmaxf(sredS[2], sredS[3]));
  __syncthreads();
  const float M = sML[0];

  {
    const float adj = __expf(mloc - M);
    lloc *= adj;
    #pragma unroll
    for (int k = 0; k < D; k++) acc[k] *= adj;
  }

  // ---- block sums ----
  float lw = lloc;
  #pragma unroll
  for (int off = 32; off; off >>= 1) lw += __shfl_xor(lw, off);
  #pragma unroll
  for (int f = 0; f < F; f++) {
    float vs = vsum[f];
    #pragma unroll
    for (int off = 32; off; off >>= 1) vs += __shfl_xor(vs, off);
    if (lane == 0) sred[wv][65 + f] = vs;
  }
  if (lane == 0) sred[wv][64] = lw;
  #pragma unroll
  for (int k = 0; k < D; k++) {
    float a = acc[k], e = esum[k];
    #pragma unroll
    for (int off = 32; off; off >>= 1) { a += __shfl_xor(a, off); e += __shfl_xor(e, off); }
    if (lane == 0) { sred[wv][k] = a; sred[wv][D + k] = e; }
  }
  __syncthreads();
  if (tid == 0) sML[1] = sred[0][64] + sred[1][64] + sred[2][64] + sred[3][64];
  __syncthreads();
  const float L    = sML[1];
  const float invL = 1.f / L;

  // ---- attention weights out ----
  out_attn[(size_t)b * SV + tid] = __expf(sc0 - M) * invL;
  if (has2) out_attn[(size_t)b * SV + tid + BDIM] = __expf(sc1 - M) * invL;

  // ---- emb_out + context:  ctx = emb_out + (esum + vsum@W_num + 511*b_num + mix_q)/S ----
  if (tid < D) {
    const float a  = sred[0][tid] + sred[1][tid] + sred[2][tid] + sred[3][tid];
    const float e  = sred[0][D + tid] + sred[1][D + tid] + sred[2][D + tid] + sred[3][D + tid];
    float vs[F];
    #pragma unroll
    for (int f = 0; f < F; f++) vs[f] = sred[0][65 + f] + sred[1][65 + f] + sred[2][65 + f] + sred[3][65 + f];
    const float vproj = vs[0] * sWnum[tid] + vs[1] * sWnum[D + tid]
                      + vs[2] * sWnum[2 * D + tid] + vs[3] * sWnum[3 * D + tid];
    const float mixsum = e + vproj + (float)SV * sbnum[tid];
    const float eo = a * invL;
    out_emb[(size_t)b * D + tid] = eo;
    sctx[tid] = eo + (mixsum + smixq[tid]) * (1.f / (float)S);
  }
  __syncthreads();

  // ---- predictor head on wave 0 ----
  if (tid < H) {
    float hv = bp[tid];
    #pragma unroll
    for (int d = 0; d < D; d++) hv += sctx[d] * sWp[d * H + tid];
    hv = fmaxf(hv, 0.f);
    float mu = hv;
    #pragma unroll
    for (int off = 32; off; off >>= 1) mu += __shfl_xor(mu, off);
    mu *= (1.f / 64.f);
    const float dv = hv - mu;
    float vv = dv * dv;
    #pragma unroll
    for (int off = 32; off; off >>= 1) vv += __shfl_xor(vv, off);
    vv *= (1.f / 64.f);
    const float hn = dv * rsqrtf(vv + 1e-3f) * ln_g[tid] + ln_b[tid];
    out_h[(size_t)b * H + tid] = hn;
    float s0 = hn * Ws[2 * tid], s1 = hn * Ws[2 * tid + 1];
    #pragma unroll
    for (int off = 32; off; off >>= 1) { s0 += __shfl_xor(s0, off); s1 += __shfl_xor(s1, off); }
    if (tid == 0) {
      const float mx = fmaxf(s0, s1);
      const float e0 = __expf(s0 - mx), e1 = __expf(s1 - mx);
      const float inv = 1.f / (e0 + e1);
      out_score[(size_t)b * 2]     = e0 * inv;
      out_score[(size_t)b * 2 + 1] = e1 * inv;
    }
  }
}

// ================= fallback (no-workspace) kernel: per-row GEMV =================
__global__ __launch_bounds__(BDIM) void attn_fused_gemv(
    const float* __restrict__ values, const int* __restrict__ names,
    const float* __restrict__ emb,
    const float* __restrict__ W_num, const float* __restrict__ b_num,
    const float* __restrict__ Wq,    const float* __restrict__ bq,
    const float* __restrict__ Wv,    const float* __restrict__ bv,
    const float* __restrict__ attn_scale,
    const float* __restrict__ Wp,    const float* __restrict__ bp,
    const float* __restrict__ ln_g,  const float* __restrict__ ln_b,
    const float* __restrict__ Ws,
    float* __restrict__ out_score, float* __restrict__ out_emb,
    float* __restrict__ out_attn,  float* __restrict__ out_h)
{
  __shared__ float sWnum[F * D];
  __shared__ float sbnum[D];
  __shared__ float sWq[D * D];
  __shared__ float sWv[D * D];
  __shared__ float sbv[D];
  __shared__ float sscale[D];
  __shared__ float sq[D];
  __shared__ float smixq[D];
  __shared__ float sred[4][2 * D];
  __shared__ float sredS[4];
  __shared__ float sML[2];
  __shared__ float sctx[D];
  __shared__ float sWp[D * H];

  const int b    = blockIdx.x;
  const int tid  = threadIdx.x;
  const int lane = tid & 63;
  const int wv   = tid >> 6;

  for (int i = tid; i < F * D; i += BDIM) sWnum[i] = W_num[i];
  if (tid < D) { sbnum[tid] = b_num[tid]; sbv[tid] = bv[tid]; sscale[tid] = attn_scale[tid]; }
  for (int i = tid; i < D * D; i += BDIM) { sWq[i] = Wq[i]; sWv[i] = Wv[i]; }
  for (int i = tid; i < D * H; i += BDIM) sWp[i] = Wp[i];
  __syncthreads();

  if (tid < D) {
    const int    name = names[b * S + (S - 1)];
    const float* vr   = values + (size_t)(b * S + (S - 1)) * F;
    smixq[tid] = emb[(size_t)name * D + tid] + sbnum[tid]
               + vr[0] * sWnum[tid] + vr[1] * sWnum[D + tid]
               + vr[2] * sWnum[2 * D + tid] + vr[3] * sWnum[3 * D + tid];
  }
  __syncthreads();
  if (tid < D) {
    float a = bq[tid];
    #pragma unroll
    for (int k = 0; k < D; k++) a += smixq[k] * sWq[k * D + tid];
    sq[tid] = a;
  }
  __syncthreads();

  float msum[D], acc[D];
  #pragma unroll
  for (int k = 0; k < D; k++) { msum[k] = 0.f; acc[k] = 0.f; }
  float mloc = -INFINITY, lloc = 0.f;
  float sc0 = 0.f, sc1 = 0.f;
  const bool has2 = (tid < SV - BDIM);

  auto row = [&](int j, float& sout) {
    const int    name = names[b * S + j];
    const float4 v4   = *reinterpret_cast<const float4*>(values + (size_t)(b * S + j) * F);
    const float4* e4p = reinterpret_cast<const float4*>(emb + (size_t)name * D);
    float mix[D];
    #pragma unroll
    for (int c = 0; c < 8; c++) {
      const float4 e = e4p[c];
      mix[4 * c] = e.x; mix[4 * c + 1] = e.y; mix[4 * c + 2] = e.z; mix[4 * c + 3] = e.w;
    }
    #pragma unroll
    for (int k = 0; k < D; k++) {
      mix[k] += sbnum[k] + v4.x * sWnum[k] + v4.y * sWnum[D + k]
              + v4.z * sWnum[2 * D + k] + v4.w * sWnum[3 * D + k];
      msum[k] += mix[k];
    }
    float val[D];
    #pragma unroll
    for (int k = 0; k < D; k++) val[k] = sbv[k];
    for (int m = 0; m < D; m++) {
      const float mv = mix[m];
      #pragma unroll
      for (int k = 0; k < D; k++) val[k] += mv * sWv[m * D + k];
    }
    float s = 0.f;
    #pragma unroll
    for (int k = 0; k < D; k++) s += sscale[k] * fast_tanh(sq[k] + val[k]);
    sout = s;
    float w;
    if (s > mloc) {
      const float sf = __expf(mloc - s);
      lloc *= sf;
      #pragma unroll
      for (int k = 0; k < D; k++) acc[k] *= sf;
      mloc = s; w = 1.f;
    } else {
      w = __expf(s - mloc);
    }
    lloc += w;
    #pragma unroll
    for (int k = 0; k < D; k++) acc[k] += w * val[k];
  };

  row(tid, sc0);
  if (has2) row(tid + BDIM, sc1);

  float mw = mloc;
  #pragma unroll
  for (int off = 32; off; off >>= 1) mw = fmaxf(mw, __shfl_xor(mw, off));
  if (lane == 0) sredS[wv] = mw;
  __syncthreads();
  if (tid == 0) sML[0] = fmaxf(fmaxf(sredS[0], sredS[1]), fmaxf(sredS[2], sredS[3]));
  __syncthreads();
  const float M = sML[0];
  {
    const float adj = __expf(mloc - M);
    lloc *= adj;
    #pragma unroll
    for (int k = 0; k < D; k++) acc[k] *= adj;
  }
  float lw = lloc;
  #pragma unroll
  for (int off = 32; off; off >>= 1) lw += __shfl_xor(lw, off);
  if (lane == 0) sredS[wv] = lw;
  #pragma unroll
  for (int k = 0; k < D; k++) {
    float a = acc[k], mm = msum[k];
    #pragma unroll
    for (int off = 32; off; off >>= 1) { a += __shfl_xor(a, off); mm += __shfl_xor(mm, off); }
    if (lane == 0) { sred[wv][k] = a; sred[wv][D + k] = mm; }
  }
  __syncthreads();
  if (tid == 0) sML[1] = sredS[0] + sredS[1] + sredS[2] + sredS[3];
  __syncthreads();
  const float L    = sML[1];
  const float invL = 1.f / L;

  out_attn[(size_t)b * SV + tid] = __expf(sc0 - M) * invL;
  if (has2) out_attn[(size_t)b * SV + tid + BDIM] = __expf(sc1 - M) * invL;

  if (tid < D) {
    const float a  = sred[0][tid] + sred[1][tid] + sred[2][tid] + sred[3][tid];
    const float mm = sred[0][D + tid] + sred[1][D + tid] + sred[2][D + tid] + sred[3][D + tid];
    const float eo = a * invL;
    out_emb[(size_t)b * D + tid] = eo;
    sctx[tid] = eo + (mm + smixq[tid]) * (1.f / (float)S);
  }
  __syncthreads();

  if (tid < H) {
    float hv = bp[tid];
    #pragma unroll
    for (int d = 0; d < D; d++) hv += sctx[d] * sWp[d * H + tid];
    hv = fmaxf(hv, 0.f);
    float mu = hv;
    #pragma unroll
    for (int off = 32; off; off >>= 1) mu += __shfl_xor(mu, off);
    mu *= (1.f / 64.f);
    const float dv = hv - mu;
    float vv = dv * dv;
    #pragma unroll
    for (int off = 32; off; off >>= 1) vv += __shfl_xor(vv, off);
    vv *= (1.f / 64.f);
    const float hn = dv * rsqrtf(vv + 1e-3f) * ln_g[tid] + ln_b[tid];
    out_h[(size_t)b * H + tid] = hn;
    float s0 = hn * Ws[2 * tid], s1 = hn * Ws[2 * tid + 1];
    #pragma unroll
    for (int off = 32; off; off >>= 1) { s0 += __shfl_xor(s0, off); s1 += __shfl_xor(s1, off); }
    if (tid == 0) {
      const float mx = fmaxf(s0, s1);
      const float e0 = __expf(s0 - mx), e1 = __expf(s1 - mx);
      const float inv = 1.f / (e0 + e1);
      out_score[(size_t)b * 2]     = e0 * inv;
      out_score[(size_t)b * 2 + 1] = e1 * inv;
    }
  }
}

extern "C" void kernel_launch(void* const* d_in, const int* in_sizes, int n_in,
                              void* d_out, int out_size, void* d_ws, size_t ws_size,
                              hipStream_t stream) {
  const float* values = (const float*)d_in[0];
  const int*   names  = (const int*)d_in[1];
  const float* emb    = (const float*)d_in[2];
  const float* W_num  = (const float*)d_in[3];
  const float* b_num  = (const float*)d_in[4];
  const float* Wq     = (const float*)d_in[5];
  const float* bq     = (const float*)d_in[6];
  const float* Wv     = (const float*)d_in[7];
  const float* bv     = (const float*)d_in[8];
  const float* scal   = (const float*)d_in[9];
  const float* Wp     = (const float*)d_in[10];
  const float* bp     = (const float*)d_in[11];
  const float* ln_g   = (const float*)d_in[12];
  const float* ln_b   = (const float*)d_in[13];
  const float* Ws     = (const float*)d_in[14];

  float* out      = (float*)d_out;
  float* o_score  = out;
  float* o_emb    = o_score + (size_t)Bsz * 2;
  float* o_attn   = o_emb   + (size_t)Bsz * D;
  float* o_h      = o_attn  + (size_t)Bsz * SV;

  const size_t tab_bytes = (size_t)VOCAB * 64 * sizeof(float);
  if (ws_size >= tab_bytes) {
    float* T = (float*)d_ws;
    hipLaunchKernelGGL(build_table, dim3((VOCAB + 7) / 8), dim3(BDIM), 0, stream, emb, Wv, T, VOCAB);
    hipLaunchKernelGGL(attn_fused_tab, dim3(Bsz), dim3(BDIM), 0, stream,
                       values, names, T, W_num, b_num, Wq, bq, Wv, bv, scal,
                       Wp, bp, ln_g, ln_b, Ws, o_score, o_emb, o_attn, o_h);
  } else {
    hipLaunchKernelGGL(attn_fused_gemv, dim3(Bsz), dim3(BDIM), 0, stream,
                       values, names, emb, W_num, b_num, Wq, bq, Wv, bv, scal,
                       Wp, bp, ln_g, ln_b, Ws, o_score, o_emb, o_attn, o_h);
  }
}